// Round 2
// baseline (1109.107 us; speedup 1.0000x reference)
//
#include <hip/hip_runtime.h>
#include <math.h>

#define BDIM 32
#define CDIM 256
#define HDIM 128
#define WDIM 128
#define HW   (HDIM * WDIM)   // 16384
#define HW4  (HW / 4)        // 4096
#define NPOS  ((size_t)BDIM * HW)    // 524288 floats per [B,H,W] buffer
#define NPOS4 (BDIM * HW4)           // 131072 float4 positions
#define CSPLIT 8
#define CCHUNK (CDIM / CSPLIT)  // 32

typedef float v4f __attribute__((ext_vector_type(4)));

// ---------------------------------------------------------------------------
// Kernel 1: partial channel-wise sum & max of y over CDIM/P channels.
// grid (512, P). P=2 doubles resident waves (8 -> 16 per CU) in case the
// single-stage version was latency-bound. Raw sums stored; 1/C folded into
// conv weights downstream. y loads are nontemporal (pure streaming data).
// ---------------------------------------------------------------------------
template<int P>
__global__ __launch_bounds__(256) void reduce_kernel(
    const v4f* __restrict__ y,
    v4f* __restrict__ sumb,    // [P][NPOS4]
    v4f* __restrict__ maxb)    // [P][NPOS4]
{
    const int idx = blockIdx.x * 256 + threadIdx.x;   // [0, NPOS4)
    const int b   = idx >> 12;                        // / HW4
    const int hw4 = idx & (HW4 - 1);
    const int c0  = blockIdx.y * (CDIM / P);
    const v4f* yp = y + (size_t)(b * CDIM + c0) * HW4 + hw4;

    v4f s0 = 0.f, s1 = 0.f, s2 = 0.f, s3 = 0.f;
    v4f m; m.x = m.y = m.z = m.w = -INFINITY;

    #pragma unroll 4
    for (int c = 0; c < CDIM / P; c += 4) {
        v4f v0 = __builtin_nontemporal_load(&yp[(size_t)(c + 0) * HW4]);
        v4f v1 = __builtin_nontemporal_load(&yp[(size_t)(c + 1) * HW4]);
        v4f v2 = __builtin_nontemporal_load(&yp[(size_t)(c + 2) * HW4]);
        v4f v3 = __builtin_nontemporal_load(&yp[(size_t)(c + 3) * HW4]);

        s0 += v0; s1 += v1; s2 += v2; s3 += v3;

        m.x = fmaxf(m.x, fmaxf(fmaxf(v0.x, v1.x), fmaxf(v2.x, v3.x)));
        m.y = fmaxf(m.y, fmaxf(fmaxf(v0.y, v1.y), fmaxf(v2.y, v3.y)));
        m.z = fmaxf(m.z, fmaxf(fmaxf(v0.z, v1.z), fmaxf(v2.z, v3.z)));
        m.w = fmaxf(m.w, fmaxf(fmaxf(v0.w, v1.w), fmaxf(v2.w, v3.w)));
    }

    v4f s = (s0 + s1) + (s2 + s3);   // raw sum (not divided)
    sumb[(size_t)blockIdx.y * NPOS4 + idx] = s;
    maxb[(size_t)blockIdx.y * NPOS4 + idx] = m;
}

// ---------------------------------------------------------------------------
// Kernel 2: gate = sigmoid(conv3x3([sum/C ; max], w)). Combines the P
// partial buffers inline (everything L2-resident, ~10 MiB). 1/C folded
// into the avg-channel weights. Cross-correlation (no kernel flip).
// ---------------------------------------------------------------------------
template<int P>
__global__ __launch_bounds__(256) void gate_kernel(
    const float* __restrict__ sumb,   // [P][NPOS]
    const float* __restrict__ maxb,   // [P][NPOS]
    const float* __restrict__ wgt,    // [1,2,3,3]: wgt[0..8]=avg-ch, wgt[9..17]=max-ch
    v4f* __restrict__ gate)
{
    const int idx = blockIdx.x * 256 + threadIdx.x;   // [0, NPOS4)
    const int b   = idx >> 12;
    const int hw4 = idx & (HW4 - 1);
    const int hw  = hw4 << 2;
    const int h   = hw >> 7;          // / W
    const int w0  = hw & (WDIM - 1);

    const float inv = 1.0f / (float)CDIM;
    float wa[9], wm[9];
    #pragma unroll
    for (int i = 0; i < 9; ++i) { wa[i] = wgt[i] * inv; wm[i] = wgt[9 + i]; }

    const float* sb = sumb + (size_t)b * HW;
    const float* mb = maxb + (size_t)b * HW;

    float g0 = 0.f, g1 = 0.f, g2 = 0.f, g3 = 0.f;

    #pragma unroll
    for (int kh = 0; kh < 3; ++kh) {
        const int r = h - 1 + kh;
        if (r < 0 || r >= HDIM) continue;   // zero padding rows contribute 0
        const float* sr = sb + r * WDIM + w0;
        const float* mr = mb + r * WDIM + w0;
        float A[6], M[6];
        #pragma unroll
        for (int j = 0; j < 6; ++j) {
            const int col = w0 + j - 1;
            const bool v = (col >= 0) && (col < WDIM);
            float s = 0.f, mx = 0.f;    // conv-input zero padding
            if (v) {
                s  = sr[j - 1];
                mx = mr[j - 1];
                if (P == 2) {
                    s  += sr[NPOS + j - 1];
                    mx  = fmaxf(mx, mr[NPOS + j - 1]);
                }
            }
            A[j] = s; M[j] = mx;
        }
        #pragma unroll
        for (int kw = 0; kw < 3; ++kw) {
            const float fa = wa[kh * 3 + kw];
            const float fm = wm[kh * 3 + kw];
            g0 += A[0 + kw] * fa + M[0 + kw] * fm;
            g1 += A[1 + kw] * fa + M[1 + kw] * fm;
            g2 += A[2 + kw] * fa + M[2 + kw] * fm;
            g3 += A[3 + kw] * fa + M[3 + kw] * fm;
        }
    }

    v4f o;
    o.x = 1.0f / (1.0f + __expf(-g0));
    o.y = 1.0f / (1.0f + __expf(-g1));
    o.z = 1.0f / (1.0f + __expf(-g2));
    o.w = 1.0f / (1.0f + __expf(-g3));
    gate[idx] = o;
}

// ---------------------------------------------------------------------------
// Kernel 3: out[b,c,h,w] = x[b,c,h,w] * gate[b,h,w]
// grid (512, CSPLIT). x/out are nontemporal streams; gate stays cached.
// ---------------------------------------------------------------------------
__global__ __launch_bounds__(256) void apply_kernel(
    const v4f* __restrict__ x,
    const v4f* __restrict__ gate,
    v4f* __restrict__ out)
{
    const int idx = blockIdx.x * 256 + threadIdx.x;   // [0, NPOS4)
    const int b   = idx >> 12;
    const int hw4 = idx & (HW4 - 1);

    const v4f g = gate[idx];

    const int c0 = blockIdx.y * CCHUNK;
    const size_t base = (size_t)(b * CDIM + c0) * HW4 + hw4;
    const v4f* xp = x + base;
    v4f*       op = out + base;

    #pragma unroll 4
    for (int c = 0; c < CCHUNK; ++c) {
        v4f v = __builtin_nontemporal_load(&xp[(size_t)c * HW4]);
        v *= g;
        __builtin_nontemporal_store(v, &op[(size_t)c * HW4]);
    }
}

extern "C" void kernel_launch(void* const* d_in, const int* in_sizes, int n_in,
                              void* d_out, int out_size, void* d_ws, size_t ws_size,
                              hipStream_t stream)
{
    const float* x      = (const float*)d_in[0];
    const float* y      = (const float*)d_in[1];
    const float* conv_w = (const float*)d_in[2];
    float*       out    = (float*)d_out;

    const int nBlocks = NPOS4 / 256;          // 512

    // P=2 layout: sum[2] | max[2] | gate  -> 5 * NPOS floats = 10 MiB
    // P=1 layout: sum    | max    | gate  -> 3 * NPOS floats =  6 MiB
    const size_t need2 = 5 * NPOS * sizeof(float);

    if (ws_size >= need2) {
        float* sumb = (float*)d_ws;
        float* maxb = sumb + 2 * NPOS;
        float* gate = maxb + 2 * NPOS;

        dim3 gridR(nBlocks, 2);
        reduce_kernel<2><<<gridR, 256, 0, stream>>>(
            (const v4f*)y, (v4f*)sumb, (v4f*)maxb);
        gate_kernel<2><<<nBlocks, 256, 0, stream>>>(
            sumb, maxb, conv_w, (v4f*)gate);

        dim3 grid3(nBlocks, CSPLIT);
        apply_kernel<<<grid3, 256, 0, stream>>>(
            (const v4f*)x, (const v4f*)gate, (v4f*)out);
    } else {
        float* sumb = (float*)d_ws;
        float* maxb = sumb + NPOS;
        float* gate = maxb + NPOS;

        dim3 gridR(nBlocks, 1);
        reduce_kernel<1><<<gridR, 256, 0, stream>>>(
            (const v4f*)y, (v4f*)sumb, (v4f*)maxb);
        gate_kernel<1><<<nBlocks, 256, 0, stream>>>(
            sumb, maxb, conv_w, (v4f*)gate);

        dim3 grid3(nBlocks, CSPLIT);
        apply_kernel<<<grid3, 256, 0, stream>>>(
            (const v4f*)x, (const v4f*)gate, (v4f*)out);
    }
}